// Round 17
// baseline (1428.111 us; speedup 1.0000x reference)
//
#include <hip/hip_runtime.h>

#define N_ROWS 65536
#define NE 1024
#define ED 64
#define ERR_GAP 8e-5f

// measurement round: idempotent reps to surface both unknowns in top-5
#define REP_DIST 6
#define REP_EX   24

static const size_t OFF_ZQ = 1;
static const size_t OFF_ME = 1 + 4194304;
static const size_t OFF_IDX = OFF_ME + (size_t)N_ROWS * NE;
#define ME_FLOATS ((size_t)N_ROWS * NE)   // 67108864

#define SC_CBF  0
#define SC_Z2   65536
#define SC_FLAG 131072

typedef __attribute__((ext_vector_type(8))) short short8v;
typedef __attribute__((ext_vector_type(4))) float f32x4;

__device__ __forceinline__ unsigned bf16_rne(float v) {
  unsigned u = __float_as_uint(v);
  return (u + 0x7FFFu + ((u >> 16) & 1u)) >> 16;
}

__device__ __forceinline__ void gld16(const void* g, void* l) {
  __builtin_amdgcn_global_load_lds(
      (const __attribute__((address_space(1))) void*)g,
      (__attribute__((address_space(3))) void*)l, 16, 0, 0);
}

// ---- zero-fill the one-hot region ----
__global__ __launch_bounds__(256) void k_fill(float* __restrict__ me) {
  const size_t n4 = (ME_FLOATS - 3) >> 2;
  float4* __restrict__ p4 = reinterpret_cast<float4*>(me + 3);
  const size_t stride = (size_t)gridDim.x * blockDim.x;
  const float4 zero4 = make_float4(0.f, 0.f, 0.f, 0.f);
  for (size_t i = blockIdx.x * (size_t)blockDim.x + threadIdx.x; i < n4; i += stride)
    p4[i] = zero4;
  if (blockIdx.x == 0 && threadIdx.x == 0) {
    me[0] = 0.f; me[1] = 0.f; me[2] = 0.f;
    me[ME_FLOATS - 1] = 0.f;
  }
}

// ---- fused: codebook split + e2 (bit-exact) ----
__global__ __launch_bounds__(256) void k_e2cb(const float* __restrict__ cb,
                                              float* __restrict__ e2,
                                              short* __restrict__ cbfrag) {
  const int tid = blockIdx.x * 256 + threadIdx.x;
  const int ct = tid >> 6, lane = tid & 63;
  const int col = ct * 16 + (lane & 15);
  const int k0 = (lane >> 4) * 8;
  const float* __restrict__ ep = cb + (size_t)col * ED + k0;
  short* __restrict__ o = cbfrag + (size_t)ct * 2048 + lane * 8;
  #pragma unroll
  for (int ks = 0; ks < 2; ++ks) {
    short h[8], lo[8];
    #pragma unroll
    for (int i = 0; i < 8; ++i) {
      const float v = ep[ks * 32 + i];
      const unsigned hb = bf16_rne(v);
      const float res = v - __uint_as_float(hb << 16);
      h[i] = (short)hb; lo[i] = (short)bf16_rne(res);
    }
    *(short8v*)(o + (size_t)(0 * 2 + ks) * 512) = *(short8v*)h;
    *(short8v*)(o + (size_t)(1 * 2 + ks) * 512) = *(short8v*)lo;
  }
  if (threadIdx.x < 64) {
    const int j = blockIdx.x * 64 + threadIdx.x;
    const float* __restrict__ e = cb + (size_t)j * ED;
    float r[8];
    #pragma unroll
    for (int i = 0; i < 8; ++i) {
      float v = e[i]; float q = v * v;
      asm volatile("" : "+v"(q)); r[i] = q;
    }
    #pragma unroll
    for (int k = 1; k < 8; ++k)
      #pragma unroll
      for (int i = 0; i < 8; ++i) {
        float v = e[8 * k + i]; float q = v * v;
        asm volatile("" : "+v"(q)); r[i] += q;
      }
    e2[j] = ((r[0] + r[1]) + (r[2] + r[3])) + ((r[4] + r[5]) + (r[6] + r[7]));
  }
}

// ---- fused dist (r15 structure), repeated REP_DIST x ----
__global__ __launch_bounds__(256, 4) void k_dist(const float* __restrict__ z,
    const short* __restrict__ cbfrag, const float* __restrict__ e2g,
    float* __restrict__ z2g, float* __restrict__ idxf, int* __restrict__ flag) {
  __shared__ float4 smem4[2320];
  short* lBs = (short*)smem4;
  float* e2l = (float*)(smem4 + 2048);
  float* z2l = (float*)(smem4 + 2304);
  float (*lzf)[65] = (float(*)[65])smem4;

  const int t = threadIdx.x, w = t >> 6, lane = t & 63;
  const int row0 = blockIdx.x * 64;
  const int rl = w * 16 + (lane & 15);
  const int n0 = row0 + rl;
  const int bb = n0 >> 10, hw = n0 & 1023;
  const float* __restrict__ zp = z + (size_t)bb * 65536 + hw;
  const int k0 = (lane >> 4) * 8;

  #pragma unroll 1
  for (int rep = 0; rep < REP_DIST; ++rep) {
    gld16(e2g + w * 256 + lane * 4, e2l + w * 256);

    #pragma unroll
    for (int ks = 0; ks < 2; ++ks)
      #pragma unroll
      for (int i = 0; i < 8; ++i)
        lzf[ks * 32 + k0 + i][rl] = zp[(size_t)(ks * 32 + k0 + i) << 10];
    __syncthreads();

    short8v a[2][2];
    #pragma unroll
    for (int ks = 0; ks < 2; ++ks) {
      short h[8], lo[8];
      #pragma unroll
      for (int i = 0; i < 8; ++i) {
        const float v = lzf[ks * 32 + k0 + i][rl];
        const unsigned hb = bf16_rne(v);
        const float res = v - __uint_as_float(hb << 16);
        h[i] = (short)hb; lo[i] = (short)bf16_rne(res);
      }
      a[0][ks] = *(short8v*)h;
      a[1][ks] = *(short8v*)lo;
    }
    if (t < 64) {
      float r[8];
      #pragma unroll
      for (int i = 0; i < 8; ++i) {
        const float v = lzf[i][t];
        float q = v * v; asm volatile("" : "+v"(q)); r[i] = q;
      }
      #pragma unroll
      for (int k = 1; k < 8; ++k)
        #pragma unroll
        for (int i = 0; i < 8; ++i) {
          const float v = lzf[8 * k + i][t];
          float q = v * v; asm volatile("" : "+v"(q)); r[i] += q;
        }
      const float z2v = ((r[0] + r[1]) + (r[2] + r[3])) + ((r[4] + r[5]) + (r[6] + r[7]));
      z2g[row0 + t] = z2v;
      z2l[t] = z2v;
    }
    __syncthreads();

    #pragma unroll
    for (int i = 0; i < 4; ++i) {
      const int s = w * 4 + i;
      gld16(cbfrag + s * 512 + lane * 8, lBs + s * 512);
    }
    float z2r[4];
    #pragma unroll
    for (int reg = 0; reg < 4; ++reg)
      z2r[reg] = z2l[w * 16 + (lane >> 4) * 4 + reg];
    float Tm[4], Ts[4]; int Tb[4];
    #pragma unroll
    for (int reg = 0; reg < 4; ++reg) { Tm[reg] = 1e30f; Ts[reg] = 1e30f; Tb[reg] = 0; }
    __syncthreads();

    int buf = 0;
    for (int c = 0; c < 16; ++c) {
      if (c < 15) {
        #pragma unroll
        for (int i = 0; i < 4; ++i) {
          const int s = w * 4 + i;
          gld16(cbfrag + (size_t)(c + 1) * 8192 + s * 512 + lane * 8,
                lBs + (buf ^ 1) * 8192 + s * 512);
        }
      }
      #pragma unroll 1
      for (int ctl = 0; ctl < 4; ++ctl) {
        short8v bfr[2][2];
        #pragma unroll
        for (int hl = 0; hl < 2; ++hl)
          #pragma unroll
          for (int ks = 0; ks < 2; ++ks)
            bfr[hl][ks] = *(const short8v*)(lBs + buf * 8192 +
                (ctl * 4 + hl * 2 + ks) * 512 + lane * 8);

        f32x4 acc = (f32x4)(0.0f);
        #pragma unroll
        for (int p = 0; p < 3; ++p) {
          const int pa = (p == 2) ? 1 : 0;
          const int pb = (p == 1) ? 1 : 0;
          #pragma unroll
          for (int ks = 0; ks < 2; ++ks)
            acc = __builtin_amdgcn_mfma_f32_16x16x32_bf16(a[pa][ks], bfr[pb][ks], acc, 0, 0, 0);
        }
        const int j = c * 64 + ctl * 16 + (lane & 15);
        const float e2v = e2l[j];
        #pragma unroll
        for (int reg = 0; reg < 4; ++reg) {
          const float dd = (z2r[reg] + e2v) - 2.0f * acc[reg];
          if (dd < Tm[reg]) { Ts[reg] = Tm[reg]; Tm[reg] = dd; Tb[reg] = j; }
          else { Ts[reg] = fminf(Ts[reg], dd); }
        }
      }
      __syncthreads();
      buf ^= 1;
    }

    #pragma unroll
    for (int reg = 0; reg < 4; ++reg) {
      float m = Tm[reg], s = Ts[reg]; int bi = Tb[reg];
      #pragma unroll
      for (int off = 1; off < 16; off <<= 1) {
        const float om = __shfl_xor(m, off, 64);
        const float os = __shfl_xor(s, off, 64);
        const int   oi = __shfl_xor(bi, off, 64);
        if (om < m || (om == m && oi < bi)) { s = fminf(m, os); m = om; bi = oi; }
        else { s = fminf(s, om); }
      }
      if ((lane & 15) == 0) {
        const int n = row0 + w * 16 + (lane >> 4) * 4 + reg;
        idxf[n] = (float)bi;
        flag[n] = (s - m < ERR_GAP) ? 1 : 0;
      }
    }
    __syncthreads();   // protect LDS before next rep restages lzf over lB
  }
}

// ---- exact rescore v3 (r16 structure), repeated REP_EX x ----
__global__ __launch_bounds__(256, 2) void k_exact3(const float* __restrict__ z,
    const float* __restrict__ cb, const float* __restrict__ e2g,
    const float* __restrict__ z2g, const int* __restrict__ flag,
    float* __restrict__ idxf) {
  __shared__ float zAll[64][64];
  __shared__ float z2All[64];
  __shared__ int   rowIdx[64];
  __shared__ float bestM[64];
  __shared__ int   bestI[64];
  __shared__ float wredM[4];
  __shared__ int   wredI[4];
  __shared__ unsigned long long maskS;
  const int t = threadIdx.x, w = t >> 6, lane = t & 63;
  const int row0 = blockIdx.x * 64;

  if (t < 64) {
    const unsigned long long mk = __ballot(flag[row0 + lane] != 0);
    if (lane == 0) maskS = mk;
  }
  __syncthreads();
  const unsigned long long mask0 = maskS;
  if (mask0 == 0) return;
  const int nrows = __popcll(mask0);
  if (t < 64 && (mask0 >> t) & 1ull) {
    const int rank = __popcll(mask0 & ((1ull << t) - 1ull));
    rowIdx[rank] = row0 + t;
  }
  __syncthreads();

  #pragma unroll 1
  for (int rep = 0; rep < REP_EX; ++rep) {
    for (int i = w; i < nrows; i += 4) {
      const int n = rowIdx[i];
      const int b = n >> 10, hw = n & 1023;
      zAll[i][lane] = z[(size_t)b * 65536 + ((size_t)lane << 10) + hw];
      if (lane == 0) z2All[i] = z2g[n];
    }
    if (t < 64) { bestM[t] = 1e30f; bestI[t] = 0; }
    __syncthreads();

    #pragma unroll 1
    for (int g = 0; g < 4; ++g) {
      const int j = g * 256 + t;
      float4 er4[16];
      const float4* __restrict__ cbp = (const float4*)(cb + (size_t)j * ED);
      #pragma unroll
      for (int q = 0; q < 16; ++q) er4[q] = cbp[q];
      const float e2v = e2g[j];
      #pragma unroll 1
      for (int i = 0; i < nrows; ++i) {
        float a = 0.f;
        #pragma unroll
        for (int q = 0; q < 16; ++q) {
          a = fmaf(zAll[i][4 * q + 0], er4[q].x, a);
          a = fmaf(zAll[i][4 * q + 1], er4[q].y, a);
          a = fmaf(zAll[i][4 * q + 2], er4[q].z, a);
          a = fmaf(zAll[i][4 * q + 3], er4[q].w, a);
        }
        float d = (z2All[i] + e2v) - 2.0f * a;
        int bi = j;
        #pragma unroll
        for (int off = 1; off < 64; off <<= 1) {
          const float om = __shfl_xor(d, off, 64);
          const int   oi = __shfl_xor(bi, off, 64);
          if (om < d || (om == d && oi < bi)) { d = om; bi = oi; }
        }
        if (lane == 0) { wredM[w] = d; wredI[w] = bi; }
        __syncthreads();
        if (t == 0) {
          float m = bestM[i]; int mi = bestI[i];
          #pragma unroll
          for (int ww = 0; ww < 4; ++ww)
            if (wredM[ww] < m || (wredM[ww] == m && wredI[ww] < mi)) {
              m = wredM[ww]; mi = wredI[ww];
            }
          bestM[i] = m; bestI[i] = mi;
        }
        __syncthreads();
      }
    }
    if (t < nrows) idxf[rowIdx[t]] = (float)bestI[t];
    __syncthreads();   // protect bestM/zAll before next rep
  }
}

// ---- z_q gather + loss partial + fused one-hot scatter ----
__global__ __launch_bounds__(256) void k_zq(const float* __restrict__ z,
    const float* __restrict__ cb, const float* __restrict__ idxf,
    float* __restrict__ zq, float* __restrict__ partial, float* __restrict__ me) {
  float s = 0.f;
  #pragma unroll 1
  for (int it = 0; it < 8; ++it) {
    const int o = (it * 2048 + blockIdx.x) * 256 + threadIdx.x;
    const int b = o >> 16;
    const int d = (o >> 10) & 63;
    const int hw = o & 1023;
    const int n = (b << 10) + hw;
    const int idx = (int)idxf[n];
    const float v = cb[(size_t)idx * ED + d];
    zq[o] = v;
    if (d == 0) me[(size_t)n * NE + idx] = 1.0f;
    const float diff = z[o] - v;
    s = fmaf(diff, diff, s);
  }
  #pragma unroll
  for (int off = 32; off > 0; off >>= 1) s += __shfl_xor(s, off, 64);
  __shared__ float sh[4];
  if ((threadIdx.x & 63) == 0) sh[threadIdx.x >> 6] = s;
  __syncthreads();
  if (threadIdx.x == 0)
    partial[blockIdx.x] = (sh[0] + sh[1]) + (sh[2] + sh[3]);
}

__global__ void k_loss(const float* __restrict__ partial, float* __restrict__ out0) {
  const int t = threadIdx.x;
  double s = 0.0;
  #pragma unroll
  for (int k = 0; k < 8; ++k) s += (double)partial[t + (k << 8)];
  #pragma unroll
  for (int off = 32; off > 0; off >>= 1) s += __shfl_xor(s, off, 64);
  __shared__ double sh[4];
  if ((t & 63) == 0) sh[t >> 6] = s;
  __syncthreads();
  if (t == 0)
    out0[0] = (float)(1.25 * ((sh[0] + sh[1]) + (sh[2] + sh[3])) / 4194304.0);
}

extern "C" void kernel_launch(void* const* d_in, const int* in_sizes, int n_in,
                              void* d_out, int out_size, void* d_ws, size_t ws_size,
                              hipStream_t stream) {
  const float* z  = (const float*)d_in[0];
  const float* cb = (const float*)d_in[1];
  float* out  = (float*)d_out;
  float* zq   = out + OFF_ZQ;
  float* me   = out + OFF_ME;
  float* idxf = out + OFF_IDX;
  float* sbase = out + 4;
  short* cbfrag = (short*)(sbase + SC_CBF);
  float* z2     = sbase + SC_Z2;
  int*   flag   = (int*)(sbase + SC_FLAG);
  float* e2      = (float*)((char*)d_ws + 16);
  float* partial = (float*)((char*)d_ws + 4112);

  k_fill<<<2048, 256, 0, stream>>>(me);
  k_e2cb<<<16, 256, 0, stream>>>(cb, e2, cbfrag);
  k_dist<<<1024, 256, 0, stream>>>(z, cbfrag, e2, z2, idxf, flag);
  k_exact3<<<1024, 256, 0, stream>>>(z, cb, e2, z2, flag, idxf);
  k_zq<<<2048, 256, 0, stream>>>(z, cb, idxf, zq, partial, me);
  k_loss<<<1, 256, 0, stream>>>(partial, out);
}

// Round 18
// 247.165 us; speedup vs baseline: 5.7780x; 5.7780x over previous
//
#include <hip/hip_runtime.h>

#define N_ROWS 65536
#define NE 1024
#define ED 64
#define ERR_GAP 8e-5f

static const size_t OFF_ZQ = 1;
static const size_t OFF_ME = 1 + 4194304;
static const size_t OFF_IDX = OFF_ME + (size_t)N_ROWS * NE;
#define ME_FLOATS ((size_t)N_ROWS * NE)   // 67108864

// scratch lives in the z_q OUTPUT region (consumed before k_zq overwrites it).
#define SC_CBF  0         // cbfrag: 131072 shorts = 65536 floats
#define SC_Z2   65536     // z2: 65536 floats
#define SC_FLAG 131072    // flag: 65536 ints
// d_ws: e2 at +16 (4KB), partial at +4112 (8KB)

typedef __attribute__((ext_vector_type(8))) short short8v;
typedef __attribute__((ext_vector_type(4))) float f32x4;

__device__ __forceinline__ unsigned bf16_rne(float v) {
  unsigned u = __float_as_uint(v);
  return (u + 0x7FFFu + ((u >> 16) & 1u)) >> 16;
}

__device__ __forceinline__ void gld16(const void* g, void* l) {
  __builtin_amdgcn_global_load_lds(
      (const __attribute__((address_space(1))) void*)g,
      (__attribute__((address_space(3))) void*)l, 16, 0, 0);
}

// ---- zero-fill the one-hot region ----
__global__ __launch_bounds__(256) void k_fill(float* __restrict__ me) {
  const size_t n4 = (ME_FLOATS - 3) >> 2;
  float4* __restrict__ p4 = reinterpret_cast<float4*>(me + 3);
  const size_t stride = (size_t)gridDim.x * blockDim.x;
  const float4 zero4 = make_float4(0.f, 0.f, 0.f, 0.f);
  for (size_t i = blockIdx.x * (size_t)blockDim.x + threadIdx.x; i < n4; i += stride)
    p4[i] = zero4;
  if (blockIdx.x == 0 && threadIdx.x == 0) {
    me[0] = 0.f; me[1] = 0.f; me[2] = 0.f;
    me[ME_FLOATS - 1] = 0.f;
  }
}

// ---- fused: codebook split + e2 (bit-exact) ----
__global__ __launch_bounds__(256) void k_e2cb(const float* __restrict__ cb,
                                              float* __restrict__ e2,
                                              short* __restrict__ cbfrag) {
  const int tid = blockIdx.x * 256 + threadIdx.x;
  const int ct = tid >> 6, lane = tid & 63;
  const int col = ct * 16 + (lane & 15);
  const int k0 = (lane >> 4) * 8;
  const float* __restrict__ ep = cb + (size_t)col * ED + k0;
  short* __restrict__ o = cbfrag + (size_t)ct * 2048 + lane * 8;
  #pragma unroll
  for (int ks = 0; ks < 2; ++ks) {
    short h[8], lo[8];
    #pragma unroll
    for (int i = 0; i < 8; ++i) {
      const float v = ep[ks * 32 + i];
      const unsigned hb = bf16_rne(v);
      const float res = v - __uint_as_float(hb << 16);
      h[i] = (short)hb; lo[i] = (short)bf16_rne(res);
    }
    *(short8v*)(o + (size_t)(0 * 2 + ks) * 512) = *(short8v*)h;
    *(short8v*)(o + (size_t)(1 * 2 + ks) * 512) = *(short8v*)lo;
  }
  if (threadIdx.x < 64) {
    const int j = blockIdx.x * 64 + threadIdx.x;
    const float* __restrict__ e = cb + (size_t)j * ED;
    float r[8];
    #pragma unroll
    for (int i = 0; i < 8; ++i) {
      float v = e[i]; float q = v * v;
      asm volatile("" : "+v"(q)); r[i] = q;
    }
    #pragma unroll
    for (int k = 1; k < 8; ++k)
      #pragma unroll
      for (int i = 0; i < 8; ++i) {
        float v = e[8 * k + i]; float q = v * v;
        asm volatile("" : "+v"(q)); r[i] += q;
      }
    e2[j] = ((r[0] + r[1]) + (r[2] + r[3])) + ((r[4] + r[5]) + (r[6] + r[7]));
  }
}

// ---- fused dist (r15 structure, measured ~29us) ----
__global__ __launch_bounds__(256, 4) void k_dist(const float* __restrict__ z,
    const short* __restrict__ cbfrag, const float* __restrict__ e2g,
    float* __restrict__ z2g, float* __restrict__ idxf, int* __restrict__ flag) {
  __shared__ float4 smem4[2320];
  short* lBs = (short*)smem4;
  float* e2l = (float*)(smem4 + 2048);
  float* z2l = (float*)(smem4 + 2304);
  float (*lzf)[65] = (float(*)[65])smem4;

  const int t = threadIdx.x, w = t >> 6, lane = t & 63;
  const int row0 = blockIdx.x * 64;

  gld16(e2g + w * 256 + lane * 4, e2l + w * 256);

  const int rl = w * 16 + (lane & 15);
  const int n0 = row0 + rl;
  const int bb = n0 >> 10, hw = n0 & 1023;
  const float* __restrict__ zp = z + (size_t)bb * 65536 + hw;
  const int k0 = (lane >> 4) * 8;
  #pragma unroll
  for (int ks = 0; ks < 2; ++ks)
    #pragma unroll
    for (int i = 0; i < 8; ++i)
      lzf[ks * 32 + k0 + i][rl] = zp[(size_t)(ks * 32 + k0 + i) << 10];
  __syncthreads();

  short8v a[2][2];
  #pragma unroll
  for (int ks = 0; ks < 2; ++ks) {
    short h[8], lo[8];
    #pragma unroll
    for (int i = 0; i < 8; ++i) {
      const float v = lzf[ks * 32 + k0 + i][rl];
      const unsigned hb = bf16_rne(v);
      const float res = v - __uint_as_float(hb << 16);
      h[i] = (short)hb; lo[i] = (short)bf16_rne(res);
    }
    a[0][ks] = *(short8v*)h;
    a[1][ks] = *(short8v*)lo;
  }
  if (t < 64) {
    float r[8];
    #pragma unroll
    for (int i = 0; i < 8; ++i) {
      const float v = lzf[i][t];
      float q = v * v; asm volatile("" : "+v"(q)); r[i] = q;
    }
    #pragma unroll
    for (int k = 1; k < 8; ++k)
      #pragma unroll
      for (int i = 0; i < 8; ++i) {
        const float v = lzf[8 * k + i][t];
        float q = v * v; asm volatile("" : "+v"(q)); r[i] += q;
      }
    const float z2v = ((r[0] + r[1]) + (r[2] + r[3])) + ((r[4] + r[5]) + (r[6] + r[7]));
    z2g[row0 + t] = z2v;
    z2l[t] = z2v;
  }
  __syncthreads();

  #pragma unroll
  for (int i = 0; i < 4; ++i) {
    const int s = w * 4 + i;
    gld16(cbfrag + s * 512 + lane * 8, lBs + s * 512);
  }
  float z2r[4];
  #pragma unroll
  for (int reg = 0; reg < 4; ++reg)
    z2r[reg] = z2l[w * 16 + (lane >> 4) * 4 + reg];
  float Tm[4], Ts[4]; int Tb[4];
  #pragma unroll
  for (int reg = 0; reg < 4; ++reg) { Tm[reg] = 1e30f; Ts[reg] = 1e30f; Tb[reg] = 0; }
  __syncthreads();

  int buf = 0;
  for (int c = 0; c < 16; ++c) {
    if (c < 15) {
      #pragma unroll
      for (int i = 0; i < 4; ++i) {
        const int s = w * 4 + i;
        gld16(cbfrag + (size_t)(c + 1) * 8192 + s * 512 + lane * 8,
              lBs + (buf ^ 1) * 8192 + s * 512);
      }
    }
    #pragma unroll 1
    for (int ctl = 0; ctl < 4; ++ctl) {
      short8v bfr[2][2];
      #pragma unroll
      for (int hl = 0; hl < 2; ++hl)
        #pragma unroll
        for (int ks = 0; ks < 2; ++ks)
          bfr[hl][ks] = *(const short8v*)(lBs + buf * 8192 +
              (ctl * 4 + hl * 2 + ks) * 512 + lane * 8);

      f32x4 acc = (f32x4)(0.0f);
      #pragma unroll
      for (int p = 0; p < 3; ++p) {
        const int pa = (p == 2) ? 1 : 0;
        const int pb = (p == 1) ? 1 : 0;
        #pragma unroll
        for (int ks = 0; ks < 2; ++ks)
          acc = __builtin_amdgcn_mfma_f32_16x16x32_bf16(a[pa][ks], bfr[pb][ks], acc, 0, 0, 0);
      }
      const int j = c * 64 + ctl * 16 + (lane & 15);
      const float e2v = e2l[j];
      #pragma unroll
      for (int reg = 0; reg < 4; ++reg) {
        const float dd = (z2r[reg] + e2v) - 2.0f * acc[reg];
        if (dd < Tm[reg]) { Ts[reg] = Tm[reg]; Tm[reg] = dd; Tb[reg] = j; }
        else { Ts[reg] = fminf(Ts[reg], dd); }
      }
    }
    __syncthreads();
    buf ^= 1;
  }

  #pragma unroll
  for (int reg = 0; reg < 4; ++reg) {
    float m = Tm[reg], s = Ts[reg]; int bi = Tb[reg];
    #pragma unroll
    for (int off = 1; off < 16; off <<= 1) {
      const float om = __shfl_xor(m, off, 64);
      const float os = __shfl_xor(s, off, 64);
      const int   oi = __shfl_xor(bi, off, 64);
      if (om < m || (om == m && oi < bi)) { s = fminf(m, os); m = om; bi = oi; }
      else { s = fminf(s, om); }
    }
    if ((lane & 15) == 0) {
      const int n = row0 + w * 16 + (lane >> 4) * 4 + reg;
      idxf[n] = (float)bi;
      flag[n] = (s - m < ERR_GAP) ? 1 : 0;
    }
  }
}

// ---- exact rescore v4: wave-per-row, codes-in-lanes, NO per-thread arrays ----
// Fixes r17-measured 50us hog (VGPR=56 => er4[16] never in regs; cb re-read
// inside every dependent chain + 2 barriers/row). Here: lane scans its 16
// codes (j = lane*16+q ascending, strict <) with the verbatim sequential
// ascending-k fmaf chain; z broadcast from LDS; cb loads independent of the
// chain (prefetchable). 64-lane lex reduce == numpy first-index (r10-proven).
__global__ __launch_bounds__(256) void k_exact4(const float* __restrict__ z,
    const float* __restrict__ cb, const float* __restrict__ e2g,
    const float* __restrict__ z2g, const int* __restrict__ flag,
    float* __restrict__ idxf) {
  __shared__ float zAll[64][64];     // 16KB worst case
  __shared__ float z2All[64];
  __shared__ int   rowIdx[64];
  __shared__ unsigned long long maskS;
  const int t = threadIdx.x, w = t >> 6, lane = t & 63;
  const int row0 = blockIdx.x * 64;

  if (t < 64) {
    const unsigned long long mk = __ballot(flag[row0 + lane] != 0);
    if (lane == 0) maskS = mk;
  }
  __syncthreads();
  const unsigned long long mask0 = maskS;
  if (mask0 == 0) return;                       // uniform exit (91% won't return)
  const int nrows = __popcll(mask0);
  if (t < 64 && (mask0 >> t) & 1ull) {
    const int rank = __popcll(mask0 & ((1ull << t) - 1ull));
    rowIdx[rank] = row0 + t;
  }
  __syncthreads();
  for (int i = w; i < nrows; i += 4) {          // stage flagged z rows + z2
    const int n = rowIdx[i];
    const int b = n >> 10, hw = n & 1023;
    zAll[i][lane] = z[(size_t)b * 65536 + ((size_t)lane << 10) + hw];
    if (lane == 0) z2All[i] = z2g[n];
  }
  __syncthreads();

  // wave w handles flagged ranks w, w+4, ... (no cross-wave reduce needed)
  #pragma unroll 1
  for (int i = w; i < nrows; i += 4) {
    const float z2v = z2All[i];
    float bm = 1e30f; int bi = 0;
    #pragma unroll 1
    for (int q = 0; q < 16; ++q) {
      const int j = lane * 16 + q;
      const float* __restrict__ e = cb + (size_t)j * ED;
      float a = 0.f;
      #pragma unroll
      for (int k = 0; k < ED; ++k)
        a = fmaf(zAll[i][k], e[k], a);          // verbatim sequential chain
      const float d = (z2v + e2g[j]) - 2.0f * a;
      if (d < bm) { bm = d; bi = j; }           // ascending j, strict <
    }
    #pragma unroll
    for (int off = 1; off < 64; off <<= 1) {    // lex reduce across lanes
      const float om = __shfl_xor(bm, off, 64);
      const int   oi = __shfl_xor(bi, off, 64);
      if (om < bm || (om == bm && oi < bi)) { bm = om; bi = oi; }
    }
    if (lane == 0) idxf[rowIdx[i]] = (float)bi;
  }
}

// ---- z_q gather + loss partial + fused one-hot scatter ----
__global__ __launch_bounds__(256) void k_zq(const float* __restrict__ z,
    const float* __restrict__ cb, const float* __restrict__ idxf,
    float* __restrict__ zq, float* __restrict__ partial, float* __restrict__ me) {
  float s = 0.f;
  #pragma unroll 1
  for (int it = 0; it < 8; ++it) {
    const int o = (it * 2048 + blockIdx.x) * 256 + threadIdx.x;
    const int b = o >> 16;
    const int d = (o >> 10) & 63;
    const int hw = o & 1023;
    const int n = (b << 10) + hw;
    const int idx = (int)idxf[n];
    const float v = cb[(size_t)idx * ED + d];
    zq[o] = v;
    if (d == 0) me[(size_t)n * NE + idx] = 1.0f;
    const float diff = z[o] - v;
    s = fmaf(diff, diff, s);
  }
  #pragma unroll
  for (int off = 32; off > 0; off >>= 1) s += __shfl_xor(s, off, 64);
  __shared__ float sh[4];
  if ((threadIdx.x & 63) == 0) sh[threadIdx.x >> 6] = s;
  __syncthreads();
  if (threadIdx.x == 0)
    partial[blockIdx.x] = (sh[0] + sh[1]) + (sh[2] + sh[3]);
}

__global__ void k_loss(const float* __restrict__ partial, float* __restrict__ out0) {
  const int t = threadIdx.x;
  double s = 0.0;
  #pragma unroll
  for (int k = 0; k < 8; ++k) s += (double)partial[t + (k << 8)];
  #pragma unroll
  for (int off = 32; off > 0; off >>= 1) s += __shfl_xor(s, off, 64);
  __shared__ double sh[4];
  if ((t & 63) == 0) sh[t >> 6] = s;
  __syncthreads();
  if (t == 0)
    out0[0] = (float)(1.25 * ((sh[0] + sh[1]) + (sh[2] + sh[3])) / 4194304.0);
}

extern "C" void kernel_launch(void* const* d_in, const int* in_sizes, int n_in,
                              void* d_out, int out_size, void* d_ws, size_t ws_size,
                              hipStream_t stream) {
  const float* z  = (const float*)d_in[0];
  const float* cb = (const float*)d_in[1];
  float* out  = (float*)d_out;
  float* zq   = out + OFF_ZQ;
  float* me   = out + OFF_ME;
  float* idxf = out + OFF_IDX;
  float* sbase = out + 4;
  short* cbfrag = (short*)(sbase + SC_CBF);
  float* z2     = sbase + SC_Z2;
  int*   flag   = (int*)(sbase + SC_FLAG);
  float* e2      = (float*)((char*)d_ws + 16);
  float* partial = (float*)((char*)d_ws + 4112);

  k_fill<<<2048, 256, 0, stream>>>(me);
  k_e2cb<<<16, 256, 0, stream>>>(cb, e2, cbfrag);
  k_dist<<<1024, 256, 0, stream>>>(z, cbfrag, e2, z2, idxf, flag);
  k_exact4<<<1024, 256, 0, stream>>>(z, cb, e2, z2, flag, idxf);
  k_zq<<<2048, 256, 0, stream>>>(z, cb, idxf, zq, partial, me);
  k_loss<<<1, 256, 0, stream>>>(partial, out);
}

// Round 21
// 197.178 us; speedup vs baseline: 7.2427x; 1.2535x over previous
//
#include <hip/hip_runtime.h>

#define N_ROWS 65536
#define NE 1024
#define ED 64
#define ERR_GAP 8e-5f

static const size_t OFF_ZQ = 1;
static const size_t OFF_ME = 1 + 4194304;
static const size_t OFF_IDX = OFF_ME + (size_t)N_ROWS * NE;
#define ME_FLOATS ((size_t)N_ROWS * NE)   // 67108864

// scratch lives in the z_q OUTPUT region (consumed before k_zq overwrites it).
#define SC_CBF  0         // cbfrag: 131072 shorts = 65536 floats
#define SC_Z2   65536     // z2: 65536 floats
#define SC_FLAG 131072    // flag: 65536 ints
#define SC_CAND 196608    // cand: 65536*8 ints = 2MB
// d_ws: e2 at +16 (4KB), partial at +4112 (8KB)

typedef __attribute__((ext_vector_type(8))) short short8v;
typedef __attribute__((ext_vector_type(4))) float f32x4;

__device__ __forceinline__ unsigned bf16_rne(float v) {
  unsigned u = __float_as_uint(v);
  return (u + 0x7FFFu + ((u >> 16) & 1u)) >> 16;
}

__device__ __forceinline__ void gld16(const void* g, void* l) {
  __builtin_amdgcn_global_load_lds(
      (const __attribute__((address_space(1))) void*)g,
      (__attribute__((address_space(3))) void*)l, 16, 0, 0);
}

// ---- zero-fill the one-hot region ----
__global__ __launch_bounds__(256) void k_fill(float* __restrict__ me) {
  const size_t n4 = (ME_FLOATS - 3) >> 2;
  float4* __restrict__ p4 = reinterpret_cast<float4*>(me + 3);
  const size_t stride = (size_t)gridDim.x * blockDim.x;
  const float4 zero4 = make_float4(0.f, 0.f, 0.f, 0.f);
  for (size_t i = blockIdx.x * (size_t)blockDim.x + threadIdx.x; i < n4; i += stride)
    p4[i] = zero4;
  if (blockIdx.x == 0 && threadIdx.x == 0) {
    me[0] = 0.f; me[1] = 0.f; me[2] = 0.f;
    me[ME_FLOATS - 1] = 0.f;
  }
}

// ---- fused: codebook split + e2 (bit-exact) ----
__global__ __launch_bounds__(256) void k_e2cb(const float* __restrict__ cb,
                                              float* __restrict__ e2,
                                              short* __restrict__ cbfrag) {
  const int tid = blockIdx.x * 256 + threadIdx.x;
  const int ct = tid >> 6, lane = tid & 63;
  const int col = ct * 16 + (lane & 15);
  const int k0 = (lane >> 4) * 8;
  const float* __restrict__ ep = cb + (size_t)col * ED + k0;
  short* __restrict__ o = cbfrag + (size_t)ct * 2048 + lane * 8;
  #pragma unroll
  for (int ks = 0; ks < 2; ++ks) {
    short h[8], lo[8];
    #pragma unroll
    for (int i = 0; i < 8; ++i) {
      const float v = ep[ks * 32 + i];
      const unsigned hb = bf16_rne(v);
      const float res = v - __uint_as_float(hb << 16);
      h[i] = (short)hb; lo[i] = (short)bf16_rne(res);
    }
    *(short8v*)(o + (size_t)(0 * 2 + ks) * 512) = *(short8v*)h;
    *(short8v*)(o + (size_t)(1 * 2 + ks) * 512) = *(short8v*)lo;
  }
  if (threadIdx.x < 64) {
    const int j = blockIdx.x * 64 + threadIdx.x;
    const float* __restrict__ e = cb + (size_t)j * ED;
    float r[8];
    #pragma unroll
    for (int i = 0; i < 8; ++i) {
      float v = e[i]; float q = v * v;
      asm volatile("" : "+v"(q)); r[i] = q;
    }
    #pragma unroll
    for (int k = 1; k < 8; ++k)
      #pragma unroll
      for (int i = 0; i < 8; ++i) {
        float v = e[8 * k + i]; float q = v * v;
        asm volatile("" : "+v"(q)); r[i] += q;
      }
    e2[j] = ((r[0] + r[1]) + (r[2] + r[3])) + ((r[4] + r[5]) + (r[6] + r[7]));
  }
}

// ---- fused dist + top-3 tracking + candidate emission ----
__global__ __launch_bounds__(256, 4) void k_dist(const float* __restrict__ z,
    const short* __restrict__ cbfrag, const float* __restrict__ e2g,
    float* __restrict__ z2g, float* __restrict__ idxf, int* __restrict__ flag,
    int* __restrict__ cand) {
  __shared__ float4 smem4[2320];
  short* lBs = (short*)smem4;
  float* e2l = (float*)(smem4 + 2048);
  float* z2l = (float*)(smem4 + 2304);
  float (*lzf)[65] = (float(*)[65])smem4;

  const int t = threadIdx.x, w = t >> 6, lane = t & 63;
  const int row0 = blockIdx.x * 64;

  gld16(e2g + w * 256 + lane * 4, e2l + w * 256);

  const int rl = w * 16 + (lane & 15);
  const int n0 = row0 + rl;
  const int bb = n0 >> 10, hw = n0 & 1023;
  const float* __restrict__ zp = z + (size_t)bb * 65536 + hw;
  const int k0 = (lane >> 4) * 8;
  #pragma unroll
  for (int ks = 0; ks < 2; ++ks)
    #pragma unroll
    for (int i = 0; i < 8; ++i)
      lzf[ks * 32 + k0 + i][rl] = zp[(size_t)(ks * 32 + k0 + i) << 10];
  __syncthreads();

  short8v a[2][2];
  #pragma unroll
  for (int ks = 0; ks < 2; ++ks) {
    short h[8], lo[8];
    #pragma unroll
    for (int i = 0; i < 8; ++i) {
      const float v = lzf[ks * 32 + k0 + i][rl];
      const unsigned hb = bf16_rne(v);
      const float res = v - __uint_as_float(hb << 16);
      h[i] = (short)hb; lo[i] = (short)bf16_rne(res);
    }
    a[0][ks] = *(short8v*)h;
    a[1][ks] = *(short8v*)lo;
  }
  if (t < 64) {
    float r[8];
    #pragma unroll
    for (int i = 0; i < 8; ++i) {
      const float v = lzf[i][t];
      float q = v * v; asm volatile("" : "+v"(q)); r[i] = q;
    }
    #pragma unroll
    for (int k = 1; k < 8; ++k)
      #pragma unroll
      for (int i = 0; i < 8; ++i) {
        const float v = lzf[8 * k + i][t];
        float q = v * v; asm volatile("" : "+v"(q)); r[i] += q;
      }
    const float z2v = ((r[0] + r[1]) + (r[2] + r[3])) + ((r[4] + r[5]) + (r[6] + r[7]));
    z2g[row0 + t] = z2v;
    z2l[t] = z2v;
  }
  __syncthreads();

  #pragma unroll
  for (int i = 0; i < 4; ++i) {
    const int s = w * 4 + i;
    gld16(cbfrag + s * 512 + lane * 8, lBs + s * 512);
  }
  float z2r[4];
  #pragma unroll
  for (int reg = 0; reg < 4; ++reg)
    z2r[reg] = z2l[w * 16 + (lane >> 4) * 4 + reg];
  float Tm1[4], Tm2[4], Tm3[4]; int Tb1[4], Tb2[4];
  #pragma unroll
  for (int reg = 0; reg < 4; ++reg) {
    Tm1[reg] = 1e30f; Tm2[reg] = 1e30f; Tm3[reg] = 1e30f;
    Tb1[reg] = 0; Tb2[reg] = 0;
  }
  __syncthreads();

  int buf = 0;
  for (int c = 0; c < 16; ++c) {
    if (c < 15) {
      #pragma unroll
      for (int i = 0; i < 4; ++i) {
        const int s = w * 4 + i;
        gld16(cbfrag + (size_t)(c + 1) * 8192 + s * 512 + lane * 8,
              lBs + (buf ^ 1) * 8192 + s * 512);
      }
    }
    #pragma unroll 1
    for (int ctl = 0; ctl < 4; ++ctl) {
      short8v bfr[2][2];
      #pragma unroll
      for (int hl = 0; hl < 2; ++hl)
        #pragma unroll
        for (int ks = 0; ks < 2; ++ks)
          bfr[hl][ks] = *(const short8v*)(lBs + buf * 8192 +
              (ctl * 4 + hl * 2 + ks) * 512 + lane * 8);

      f32x4 acc = (f32x4)(0.0f);
      // pairs (a_hl,b_hl): (h,h) (h,l) (l,h); ks inner — same order as r8-r20
      #pragma unroll
      for (int p = 0; p < 3; ++p) {
        const int pa = (p == 2) ? 1 : 0;
        const int pb = (p == 1) ? 1 : 0;
        #pragma unroll
        for (int ks = 0; ks < 2; ++ks)
          acc = __builtin_amdgcn_mfma_f32_16x16x32_bf16(a[pa][ks], bfr[pb][ks], acc, 0, 0, 0);
      }
      const int j = c * 64 + ctl * 16 + (lane & 15);
      const float e2v = e2l[j];
      #pragma unroll
      for (int reg = 0; reg < 4; ++reg) {
        const float dd = (z2r[reg] + e2v) - 2.0f * acc[reg];
        if (dd < Tm1[reg]) {
          Tm3[reg] = Tm2[reg]; Tm2[reg] = Tm1[reg]; Tb2[reg] = Tb1[reg];
          Tm1[reg] = dd; Tb1[reg] = j;
        } else if (dd < Tm2[reg]) {
          Tm3[reg] = Tm2[reg]; Tm2[reg] = dd; Tb2[reg] = j;
        } else if (dd < Tm3[reg]) {
          Tm3[reg] = dd;
        }
      }
    }
    __syncthreads();
    buf ^= 1;
  }

  // epilogue: 16-lane lex reduce; candidate compaction; flag in {0, ncand, 999}
  #pragma unroll
  for (int reg = 0; reg < 4; ++reg) {
    float rm = Tm1[reg]; int ri = Tb1[reg];
    #pragma unroll
    for (int off = 1; off < 16; off <<= 1) {
      const float om = __shfl_xor(rm, off, 64);
      const int   oi = __shfl_xor(ri, off, 64);
      if (om < rm || (om == rm && oi < ri)) { rm = om; ri = oi; }
    }
    const float thr = rm + ERR_GAP;
    const bool c1 = (Tm1[reg] <= thr);
    const bool c2 = (Tm2[reg] <= thr);
    const bool c3 = (Tm3[reg] <= thr);
    const unsigned long long b1 = __ballot(c1);
    const unsigned long long b2 = __ballot(c2);
    const unsigned long long b3 = __ballot(c3);
    const int grp = lane >> 4;
    const unsigned m1m = (unsigned)((b1 >> (grp * 16)) & 0xFFFFull);
    const unsigned m2m = (unsigned)((b2 >> (grp * 16)) & 0xFFFFull);
    const unsigned m3m = (unsigned)((b3 >> (grp * 16)) & 0xFFFFull);
    const int n1 = __popc(m1m);
    const int ncand = n1 + __popc(m2m);
    const bool ovf = (m3m != 0u) || (ncand > 8);
    const int n = row0 + w * 16 + grp * 4 + reg;
    if (!ovf) {
      const unsigned below = (1u << (lane & 15)) - 1u;
      if (c1) cand[n * 8 + __popc(m1m & below)] = Tb1[reg];
      if (c2) cand[n * 8 + n1 + __popc(m2m & below)] = Tb2[reg];
    }
    if ((lane & 15) == 0) {
      idxf[n] = (float)ri;
      flag[n] = ovf ? 999 : (ncand >= 2 ? ncand : 0);
    }
  }
}

// ---- exact rescore over candidate sets (verbatim sequential chains) ----
// One WAVE per 64-row group: 256 blocks (1024 waves).
// r20 BUG FIX: the candidate chain's __shfl(zv,k) ran inside `if(lane<fn)` —
// ds_bpermute from exec-INACTIVE lanes is undefined, so k>=fn broadcasts were
// garbage. Now ALL 64 lanes stay active through the shfl chain (clamped cand
// slot for lanes>=fn), and inactive results are masked AFTER, before reduce.
__global__ __launch_bounds__(256) void k_exactC(const float* __restrict__ z,
    const float* __restrict__ cb, const float* __restrict__ e2g,
    const float* __restrict__ z2g, const int* __restrict__ flag,
    const int* __restrict__ cand, float* __restrict__ idxf) {
  const int w = threadIdx.x >> 6, lane = threadIdx.x & 63;
  const int g = blockIdx.x * 4 + w;             // 0..1023 with 256 blocks
  const int f = flag[g * 64 + lane];
  unsigned long long mask = __ballot(f != 0);
  while (mask) {
    const int bit = __ffsll((long long)mask) - 1; mask &= mask - 1;
    const int n = g * 64 + bit;
    const int fn = __shfl(f, bit, 64);
    const int b = n >> 10, hw = n & 1023;
    const float zv = z[(size_t)b * 65536 + ((size_t)lane << 10) + hw];  // lane k holds z_k
    const float z2v = z2g[n];
    if (fn != 999) {
      // candidate path — UNIFORM: every lane computes a chain (clamped slot),
      // so all 64 lanes are active for the z broadcasts.
      const int ci = cand[n * 8 + (lane < fn ? lane : 0)];
      const float* __restrict__ e = cb + (size_t)ci * ED;
      float acl = 0.f;
      #pragma unroll
      for (int k = 0; k < ED; ++k)
        acl = fmaf(__shfl(zv, k, 64), e[k], acl);   // ascending k, bit-exact
      float d = (z2v + e2g[ci]) - 2.0f * acl;
      int bi = ci;
      if (lane >= fn) { d = 1e30f; bi = 0x7FFFFFFF; }  // mask AFTER the shfls
      #pragma unroll
      for (int off = 1; off < 8; off <<= 1) {         // lex-min over <=8 lanes
        const float om = __shfl_xor(d, off, 64);
        const int   oi = __shfl_xor(bi, off, 64);
        if (om < d || (om == d && oi < bi)) { d = om; bi = oi; }
      }
      if (lane == 0) idxf[n] = (float)bi;
    } else {
      // full rescan (rare): 16 codes/lane, float4 e loads, ascending-k chain
      float bm = 1e30f; int bi = 0;
      #pragma unroll 1
      for (int q = 0; q < 16; ++q) {
        const int j = lane * 16 + q;
        const float4* __restrict__ e4 = (const float4*)(cb + (size_t)j * ED);
        float acl = 0.f;
        #pragma unroll
        for (int p = 0; p < 16; ++p) {
          const float4 ee = e4[p];
          acl = fmaf(__shfl(zv, 4 * p + 0, 64), ee.x, acl);
          acl = fmaf(__shfl(zv, 4 * p + 1, 64), ee.y, acl);
          acl = fmaf(__shfl(zv, 4 * p + 2, 64), ee.z, acl);
          acl = fmaf(__shfl(zv, 4 * p + 3, 64), ee.w, acl);
        }
        const float d = (z2v + e2g[j]) - 2.0f * acl;
        if (d < bm) { bm = d; bi = j; }               // ascending j, strict <
      }
      #pragma unroll
      for (int off = 1; off < 64; off <<= 1) {
        const float om = __shfl_xor(bm, off, 64);
        const int   oi = __shfl_xor(bi, off, 64);
        if (om < bm || (om == bm && oi < bi)) { bm = om; bi = oi; }
      }
      if (lane == 0) idxf[n] = (float)bi;
    }
  }
}

// ---- z_q gather + loss partial + fused one-hot scatter ----
__global__ __launch_bounds__(256) void k_zq(const float* __restrict__ z,
    const float* __restrict__ cb, const float* __restrict__ idxf,
    float* __restrict__ zq, float* __restrict__ partial, float* __restrict__ me) {
  float s = 0.f;
  #pragma unroll 1
  for (int it = 0; it < 8; ++it) {
    const int o = (it * 2048 + blockIdx.x) * 256 + threadIdx.x;
    const int b = o >> 16;
    const int d = (o >> 10) & 63;
    const int hw = o & 1023;
    const int n = (b << 10) + hw;
    const int idx = (int)idxf[n];
    const float v = cb[(size_t)idx * ED + d];
    zq[o] = v;
    if (d == 0) me[(size_t)n * NE + idx] = 1.0f;
    const float diff = z[o] - v;
    s = fmaf(diff, diff, s);
  }
  #pragma unroll
  for (int off = 32; off > 0; off >>= 1) s += __shfl_xor(s, off, 64);
  __shared__ float sh[4];
  if ((threadIdx.x & 63) == 0) sh[threadIdx.x >> 6] = s;
  __syncthreads();
  if (threadIdx.x == 0)
    partial[blockIdx.x] = (sh[0] + sh[1]) + (sh[2] + sh[3]);
}

__global__ void k_loss(const float* __restrict__ partial, float* __restrict__ out0) {
  const int t = threadIdx.x;
  double s = 0.0;
  #pragma unroll
  for (int k = 0; k < 8; ++k) s += (double)partial[t + (k << 8)];
  #pragma unroll
  for (int off = 32; off > 0; off >>= 1) s += __shfl_xor(s, off, 64);
  __shared__ double sh[4];
  if ((t & 63) == 0) sh[t >> 6] = s;
  __syncthreads();
  if (t == 0)
    out0[0] = (float)(1.25 * ((sh[0] + sh[1]) + (sh[2] + sh[3])) / 4194304.0);
}

extern "C" void kernel_launch(void* const* d_in, const int* in_sizes, int n_in,
                              void* d_out, int out_size, void* d_ws, size_t ws_size,
                              hipStream_t stream) {
  const float* z  = (const float*)d_in[0];
  const float* cb = (const float*)d_in[1];
  float* out  = (float*)d_out;
  float* zq   = out + OFF_ZQ;
  float* me   = out + OFF_ME;
  float* idxf = out + OFF_IDX;
  float* sbase = out + 4;
  short* cbfrag = (short*)(sbase + SC_CBF);
  float* z2     = sbase + SC_Z2;
  int*   flag   = (int*)(sbase + SC_FLAG);
  int*   cand   = (int*)(sbase + SC_CAND);
  float* e2      = (float*)((char*)d_ws + 16);
  float* partial = (float*)((char*)d_ws + 4112);

  k_fill<<<2048, 256, 0, stream>>>(me);
  k_e2cb<<<16, 256, 0, stream>>>(cb, e2, cbfrag);
  k_dist<<<1024, 256, 0, stream>>>(z, cbfrag, e2, z2, idxf, flag, cand);
  k_exactC<<<256, 256, 0, stream>>>(z, cb, e2, z2, flag, cand, idxf);
  k_zq<<<2048, 256, 0, stream>>>(z, cb, idxf, zq, partial, me);
  k_loss<<<1, 256, 0, stream>>>(partial, out);
}

// Round 22
// 164.287 us; speedup vs baseline: 8.6928x; 1.2002x over previous
//
#include <hip/hip_runtime.h>

#define N_ROWS 65536
#define NE 1024
#define ED 64
#define ERR_GAP 8e-5f

static const size_t OFF_ZQ = 1;
static const size_t OFF_ME = 1 + 4194304;
static const size_t OFF_IDX = OFF_ME + (size_t)N_ROWS * NE;
#define ME_FLOATS ((size_t)N_ROWS * NE)   // 67108864

// scratch: cbfrag in the z_q OUTPUT region (consumed by distX before zq writes).
#define SC_CBF  0         // cbfrag: 131072 shorts
// d_ws: e2 at +16 (4KB), partial at +4112 (8KB)

typedef __attribute__((ext_vector_type(8))) short short8v;
typedef __attribute__((ext_vector_type(4))) float f32x4;

__device__ __forceinline__ unsigned bf16_rne(float v) {
  unsigned u = __float_as_uint(v);
  return (u + 0x7FFFu + ((u >> 16) & 1u)) >> 16;
}

__device__ __forceinline__ void gld16(const void* g, void* l) {
  __builtin_amdgcn_global_load_lds(
      (const __attribute__((address_space(1))) void*)g,
      (__attribute__((address_space(3))) void*)l, 16, 0, 0);
}

// ---- fused: codebook split + e2 (bit-exact) ----
__global__ __launch_bounds__(256) void k_e2cb(const float* __restrict__ cb,
                                              float* __restrict__ e2,
                                              short* __restrict__ cbfrag) {
  const int tid = blockIdx.x * 256 + threadIdx.x;
  const int ct = tid >> 6, lane = tid & 63;
  const int col = ct * 16 + (lane & 15);
  const int k0 = (lane >> 4) * 8;
  const float* __restrict__ ep = cb + (size_t)col * ED + k0;
  short* __restrict__ o = cbfrag + (size_t)ct * 2048 + lane * 8;
  #pragma unroll
  for (int ks = 0; ks < 2; ++ks) {
    short h[8], lo[8];
    #pragma unroll
    for (int i = 0; i < 8; ++i) {
      const float v = ep[ks * 32 + i];
      const unsigned hb = bf16_rne(v);
      const float res = v - __uint_as_float(hb << 16);
      h[i] = (short)hb; lo[i] = (short)bf16_rne(res);
    }
    *(short8v*)(o + (size_t)(0 * 2 + ks) * 512) = *(short8v*)h;
    *(short8v*)(o + (size_t)(1 * 2 + ks) * 512) = *(short8v*)lo;
  }
  if (threadIdx.x < 64) {
    const int j = blockIdx.x * 64 + threadIdx.x;
    const float* __restrict__ e = cb + (size_t)j * ED;
    float r[8];
    #pragma unroll
    for (int i = 0; i < 8; ++i) {
      float v = e[i]; float q = v * v;
      asm volatile("" : "+v"(q)); r[i] = q;
    }
    #pragma unroll
    for (int k = 1; k < 8; ++k)
      #pragma unroll
      for (int i = 0; i < 8; ++i) {
        float v = e[8 * k + i]; float q = v * v;
        asm volatile("" : "+v"(q)); r[i] += q;
      }
    e2[j] = ((r[0] + r[1]) + (r[2] + r[3])) + ((r[4] + r[5]) + (r[6] + r[7]));
  }
}

// ---- fused: dist (MFMA) + top-3 + candidate emission + INLINE rescore ----
// Rescore is array-free (r12's inline disaster was zb[64] spills): candidates
// in LDS (overlaid on dead lB), all-lane-active shfl chains, verbatim
// sequential ascending-k fmaf, lex tie-breaks == numpy first-index.
__global__ __launch_bounds__(256, 4) void k_distX(const float* __restrict__ z,
    const float* __restrict__ cb, const short* __restrict__ cbfrag,
    const float* __restrict__ e2g, float* __restrict__ idxf) {
  __shared__ float4 smem4[2320];                 // 37120 B
  short* lBs = (short*)smem4;
  float* e2l = (float*)(smem4 + 2048);
  float* z2l = (float*)(smem4 + 2304);
  float (*lzf)[65] = (float(*)[65])smem4;
  int* candL = (int*)smem4;                      // [64][8] ints, post-loop overlay
  int* nfl   = (int*)smem4 + 512;                // [64] ints

  const int t = threadIdx.x, w = t >> 6, lane = t & 63;
  const int row0 = blockIdx.x * 64;

  gld16(e2g + w * 256 + lane * 4, e2l + w * 256);

  const int rl = w * 16 + (lane & 15);
  const int n0 = row0 + rl;
  const int bb = n0 >> 10, hw = n0 & 1023;
  const float* __restrict__ zp = z + (size_t)bb * 65536 + hw;
  const int k0 = (lane >> 4) * 8;
  #pragma unroll
  for (int ks = 0; ks < 2; ++ks)
    #pragma unroll
    for (int i = 0; i < 8; ++i)
      lzf[ks * 32 + k0 + i][rl] = zp[(size_t)(ks * 32 + k0 + i) << 10];
  __syncthreads();

  short8v a[2][2];
  #pragma unroll
  for (int ks = 0; ks < 2; ++ks) {
    short h[8], lo[8];
    #pragma unroll
    for (int i = 0; i < 8; ++i) {
      const float v = lzf[ks * 32 + k0 + i][rl];
      const unsigned hb = bf16_rne(v);
      const float res = v - __uint_as_float(hb << 16);
      h[i] = (short)hb; lo[i] = (short)bf16_rne(res);
    }
    a[0][ks] = *(short8v*)h;
    a[1][ks] = *(short8v*)lo;
  }
  if (t < 64) {
    float r[8];
    #pragma unroll
    for (int i = 0; i < 8; ++i) {
      const float v = lzf[i][t];
      float q = v * v; asm volatile("" : "+v"(q)); r[i] = q;
    }
    #pragma unroll
    for (int k = 1; k < 8; ++k)
      #pragma unroll
      for (int i = 0; i < 8; ++i) {
        const float v = lzf[8 * k + i][t];
        float q = v * v; asm volatile("" : "+v"(q)); r[i] += q;
      }
    z2l[t] = ((r[0] + r[1]) + (r[2] + r[3])) + ((r[4] + r[5]) + (r[6] + r[7]));
  }
  __syncthreads();

  #pragma unroll
  for (int i = 0; i < 4; ++i) {
    const int s = w * 4 + i;
    gld16(cbfrag + s * 512 + lane * 8, lBs + s * 512);
  }
  float z2r[4];
  #pragma unroll
  for (int reg = 0; reg < 4; ++reg)
    z2r[reg] = z2l[w * 16 + (lane >> 4) * 4 + reg];
  float Tm1[4], Tm2[4], Tm3[4]; int Tb1[4], Tb2[4];
  #pragma unroll
  for (int reg = 0; reg < 4; ++reg) {
    Tm1[reg] = 1e30f; Tm2[reg] = 1e30f; Tm3[reg] = 1e30f;
    Tb1[reg] = 0; Tb2[reg] = 0;
  }
  __syncthreads();

  int buf = 0;
  for (int c = 0; c < 16; ++c) {
    if (c < 15) {
      #pragma unroll
      for (int i = 0; i < 4; ++i) {
        const int s = w * 4 + i;
        gld16(cbfrag + (size_t)(c + 1) * 8192 + s * 512 + lane * 8,
              lBs + (buf ^ 1) * 8192 + s * 512);
      }
    }
    #pragma unroll 1
    for (int ctl = 0; ctl < 4; ++ctl) {
      short8v bfr[2][2];
      #pragma unroll
      for (int hl = 0; hl < 2; ++hl)
        #pragma unroll
        for (int ks = 0; ks < 2; ++ks)
          bfr[hl][ks] = *(const short8v*)(lBs + buf * 8192 +
              (ctl * 4 + hl * 2 + ks) * 512 + lane * 8);

      f32x4 acc = (f32x4)(0.0f);
      // pairs (a_hl,b_hl): (h,h) (h,l) (l,h); ks inner — same order as r8-r21
      #pragma unroll
      for (int p = 0; p < 3; ++p) {
        const int pa = (p == 2) ? 1 : 0;
        const int pb = (p == 1) ? 1 : 0;
        #pragma unroll
        for (int ks = 0; ks < 2; ++ks)
          acc = __builtin_amdgcn_mfma_f32_16x16x32_bf16(a[pa][ks], bfr[pb][ks], acc, 0, 0, 0);
      }
      const int j = c * 64 + ctl * 16 + (lane & 15);
      const float e2v = e2l[j];
      #pragma unroll
      for (int reg = 0; reg < 4; ++reg) {
        const float dd = (z2r[reg] + e2v) - 2.0f * acc[reg];
        if (dd < Tm1[reg]) {
          Tm3[reg] = Tm2[reg]; Tm2[reg] = Tm1[reg]; Tb2[reg] = Tb1[reg];
          Tm1[reg] = dd; Tb1[reg] = j;
        } else if (dd < Tm2[reg]) {
          Tm3[reg] = Tm2[reg]; Tm2[reg] = dd; Tb2[reg] = j;
        } else if (dd < Tm3[reg]) {
          Tm3[reg] = dd;
        }
      }
    }
    __syncthreads();   // final iter: all lB reads done; lBs dead afterward
    buf ^= 1;
  }

  // epilogue: lex reduce; candidates -> LDS; flagged rows rescored below
  #pragma unroll
  for (int reg = 0; reg < 4; ++reg) {
    float rm = Tm1[reg]; int ri = Tb1[reg];
    #pragma unroll
    for (int off = 1; off < 16; off <<= 1) {
      const float om = __shfl_xor(rm, off, 64);
      const int   oi = __shfl_xor(ri, off, 64);
      if (om < rm || (om == rm && oi < ri)) { rm = om; ri = oi; }
    }
    const float thr = rm + ERR_GAP;
    const bool c1 = (Tm1[reg] <= thr);
    const bool c2 = (Tm2[reg] <= thr);
    const bool c3 = (Tm3[reg] <= thr);
    const unsigned long long b1 = __ballot(c1);
    const unsigned long long b2 = __ballot(c2);
    const unsigned long long b3 = __ballot(c3);
    const int grp = lane >> 4;
    const unsigned m1m = (unsigned)((b1 >> (grp * 16)) & 0xFFFFull);
    const unsigned m2m = (unsigned)((b2 >> (grp * 16)) & 0xFFFFull);
    const unsigned m3m = (unsigned)((b3 >> (grp * 16)) & 0xFFFFull);
    const int n1 = __popc(m1m);
    const int ncand = n1 + __popc(m2m);
    const bool ovf = (m3m != 0u) || (ncand > 8);
    const int rowLocal = w * 16 + grp * 4 + reg;
    if (!ovf) {
      const unsigned below = (1u << (lane & 15)) - 1u;
      if (c1) candL[rowLocal * 8 + __popc(m1m & below)] = Tb1[reg];
      if (c2) candL[rowLocal * 8 + n1 + __popc(m2m & below)] = Tb2[reg];
    }
    if ((lane & 15) == 0) {
      const bool wrf = ovf || (ncand >= 2);
      nfl[rowLocal] = ovf ? 999 : (ncand >= 2 ? ncand : 0);
      if (!wrf) idxf[row0 + rowLocal] = (float)ri;
    }
  }
  __syncthreads();

  // inline rescore: wave w handles its own rows w*16..w*16+15
  #pragma unroll 1
  for (int r = 0; r < 16; ++r) {
    const int rowLocal = w * 16 + r;
    const int fn = nfl[rowLocal];          // wave-uniform (same LDS addr)
    if (fn == 0) continue;
    const int n = row0 + rowLocal;
    const int b2 = n >> 10, hw2 = n & 1023;
    const float zv = z[(size_t)b2 * 65536 + ((size_t)lane << 10) + hw2];  // lane k = z_k
    const float z2v = z2l[rowLocal];
    if (fn != 999) {
      // all 64 lanes active through the shfl chain (clamped cand slot)
      const int ci = candL[rowLocal * 8 + (lane < fn ? lane : 0)];
      const float* __restrict__ e = cb + (size_t)ci * ED;
      float acl = 0.f;
      #pragma unroll 8
      for (int k = 0; k < ED; ++k)
        acl = fmaf(__shfl(zv, k, 64), e[k], acl);   // ascending k, bit-exact
      float d = (z2v + e2l[ci]) - 2.0f * acl;
      int bi = ci;
      if (lane >= fn) { d = 1e30f; bi = 0x7FFFFFFF; }  // mask AFTER shfls
      #pragma unroll
      for (int off = 1; off < 8; off <<= 1) {
        const float om = __shfl_xor(d, off, 64);
        const int   oi = __shfl_xor(bi, off, 64);
        if (om < d || (om == d && oi < bi)) { d = om; bi = oi; }
      }
      if (lane == 0) idxf[n] = (float)bi;
    } else {
      // full rescan (rare): 16 codes/lane, float4 loads, ascending-k chain
      float bm = 1e30f; int bi = 0;
      #pragma unroll 1
      for (int q = 0; q < 16; ++q) {
        const int j = lane * 16 + q;
        const float4* __restrict__ e4 = (const float4*)(cb + (size_t)j * ED);
        float acl = 0.f;
        #pragma unroll
        for (int p = 0; p < 16; ++p) {
          const float4 ee = e4[p];
          acl = fmaf(__shfl(zv, 4 * p + 0, 64), ee.x, acl);
          acl = fmaf(__shfl(zv, 4 * p + 1, 64), ee.y, acl);
          acl = fmaf(__shfl(zv, 4 * p + 2, 64), ee.z, acl);
          acl = fmaf(__shfl(zv, 4 * p + 3, 64), ee.w, acl);
        }
        const float d = (z2v + e2l[j]) - 2.0f * acl;
        if (d < bm) { bm = d; bi = j; }
      }
      #pragma unroll
      for (int off = 1; off < 64; off <<= 1) {
        const float om = __shfl_xor(bm, off, 64);
        const int   oi = __shfl_xor(bi, off, 64);
        if (om < bm || (om == bm && oi < bi)) { bm = om; bi = oi; }
      }
      if (lane == 0) idxf[n] = (float)bi;
    }
  }
}

// ---- z_q gather + loss partials (scatter removed; one-hot owns me) ----
__global__ __launch_bounds__(256) void k_zq(const float* __restrict__ z,
    const float* __restrict__ cb, const float* __restrict__ idxf,
    float* __restrict__ zq, float* __restrict__ partial) {
  float s = 0.f;
  #pragma unroll 1
  for (int it = 0; it < 8; ++it) {
    const int o = (it * 2048 + blockIdx.x) * 256 + threadIdx.x;
    const int b = o >> 16;
    const int d = (o >> 10) & 63;
    const int hw = o & 1023;
    const int n = (b << 10) + hw;
    const int idx = (int)idxf[n];
    const float v = cb[(size_t)idx * ED + d];
    zq[o] = v;
    const float diff = z[o] - v;
    s = fmaf(diff, diff, s);
  }
  #pragma unroll
  for (int off = 32; off > 0; off >>= 1) s += __shfl_xor(s, off, 64);
  __shared__ float sh[4];
  if ((threadIdx.x & 63) == 0) sh[threadIdx.x >> 6] = s;
  __syncthreads();
  if (threadIdx.x == 0)
    partial[blockIdx.x] = (sh[0] + sh[1]) + (sh[2] + sh[3]);
}

// ---- one-hot writer (fill+hot in ONE pass, per-row LDS-hoisted idx) + loss ----
// r10's fused writer failed on per-float4 idxf loads (latency-bound @3TB/s);
// here idx is loaded 32x per block into LDS, stores fully independent.
__global__ __launch_bounds__(256) void k_onehot(const float* __restrict__ idxf,
    const float* __restrict__ partial, float* __restrict__ me,
    float* __restrict__ out0) {
  __shared__ int idxL[32];
  const int t = threadIdx.x;
  const int n0 = blockIdx.x * 32;
  if (t < 32) idxL[t] = (int)idxf[n0 + t];
  __syncthreads();
  float* __restrict__ base = me + (size_t)n0 * 1024;   // float-offset ≡1 mod 4
  float4* __restrict__ p4 = (float4*)(base + 3);       // 16B-aligned
  #pragma unroll 1
  for (int s = t; s < 8191; s += 256) {                // floats 3..32766
    const int f0 = 3 + 4 * s;
    const int row = f0 >> 10;
    const int col0 = f0 & 1023;
    float4 v;
    if (col0 <= 1020) {
      const int idx = idxL[row];
      v.x = (col0 == idx)     ? 1.0f : 0.0f;
      v.y = (col0 + 1 == idx) ? 1.0f : 0.0f;
      v.z = (col0 + 2 == idx) ? 1.0f : 0.0f;
      v.w = (col0 + 3 == idx) ? 1.0f : 0.0f;
    } else {                                           // col0 == 1023: spans rows
      v.x = (idxL[row] == 1023)    ? 1.0f : 0.0f;
      v.y = (idxL[row + 1] == 0)   ? 1.0f : 0.0f;
      v.z = (idxL[row + 1] == 1)   ? 1.0f : 0.0f;
      v.w = (idxL[row + 1] == 2)   ? 1.0f : 0.0f;
    }
    p4[s] = v;
  }
  if (t == 0) {                                        // strays: floats 0,1,2,32767
    base[0] = (idxL[0] == 0) ? 1.0f : 0.0f;
    base[1] = (idxL[0] == 1) ? 1.0f : 0.0f;
    base[2] = (idxL[0] == 2) ? 1.0f : 0.0f;
    base[32767] = (idxL[31] == 1023) ? 1.0f : 0.0f;
  }
  if (blockIdx.x == 0) {                               // fused loss reduce
    double sd = 0.0;
    #pragma unroll
    for (int k = 0; k < 8; ++k) sd += (double)partial[t + (k << 8)];
    #pragma unroll
    for (int off = 32; off > 0; off >>= 1) sd += __shfl_xor(sd, off, 64);
    __shared__ double shd[4];
    if ((t & 63) == 0) shd[t >> 6] = sd;
    __syncthreads();
    if (t == 0)
      out0[0] = (float)(1.25 * ((shd[0] + shd[1]) + (shd[2] + shd[3])) / 4194304.0);
  }
}

extern "C" void kernel_launch(void* const* d_in, const int* in_sizes, int n_in,
                              void* d_out, int out_size, void* d_ws, size_t ws_size,
                              hipStream_t stream) {
  const float* z  = (const float*)d_in[0];
  const float* cb = (const float*)d_in[1];
  float* out  = (float*)d_out;
  float* zq   = out + OFF_ZQ;
  float* me   = out + OFF_ME;
  float* idxf = out + OFF_IDX;
  float* sbase = out + 4;
  short* cbfrag = (short*)(sbase + SC_CBF);
  float* e2      = (float*)((char*)d_ws + 16);
  float* partial = (float*)((char*)d_ws + 4112);

  k_e2cb<<<16, 256, 0, stream>>>(cb, e2, cbfrag);
  k_distX<<<1024, 256, 0, stream>>>(z, cb, cbfrag, e2, idxf);
  k_zq<<<2048, 256, 0, stream>>>(z, cb, idxf, zq, partial);
  k_onehot<<<2048, 256, 0, stream>>>(idxf, partial, me, out);
}